// Round 3
// baseline (1453.384 us; speedup 1.0000x reference)
//
#include <hip/hip_runtime.h>
#include <math.h>

#define B_ 8
#define N_ 1024
#define M_ 20000
#define C_ 80
#define G_ 64
#define SLOTS 16   // N_/64
typedef unsigned long long ull;

__device__ __forceinline__ float iou1(float ax, float ay, float az, float aw,
                                      float bx, float by, float bz, float bw) {
    // legacy +1 convention, exact reference arithmetic order
    float lx = fmaxf(ax, bx), ly = fmaxf(ay, by);
    float rx = fminf(az, bz), ry = fminf(aw, bw);
    float w = fmaxf(rx - lx + 1.0f, 0.0f), h = fmaxf(ry - ly + 1.0f, 0.0f);
    float ov = w * h;
    float a1 = (az - ax + 1.0f) * (aw - ay + 1.0f);
    float a2 = (bz - bx + 1.0f) * (bw - by + 1.0f);
    return ov / (a1 + a2 - ov);
}

__global__ __launch_bounds__(64) void nms_loss_kernel(
    const int* __restrict__ pos_inds, const int* __restrict__ pos_gt,
    const float* __restrict__ gt_bboxes, const float* __restrict__ bbox_preds,
    const float* __restrict__ cls_scores, const int* __restrict__ gt_labels,
    float* __restrict__ out) {
    const int b = blockIdx.x;
    const int lane = threadIdx.x;

    __shared__ float  s_gtiou[G_ * G_];   // 16 KiB
    __shared__ ull    s_keys[N_];         //  8 KiB
    __shared__ float4 s_elem4[N_ * 2];    // 32 KiB sorted: {x0,y0,x1,y1},{g,score,area,0}

    // --- gt-gt IoU table ---
    const float* gb = gt_bboxes + (size_t)(b * G_ + lane) * 4;
    float g0 = gb[0], g1 = gb[1], g2 = gb[2], g3 = gb[3];
    for (int r = 0; r < G_; ++r) {
        float rx0 = __shfl(g0, r), ry0 = __shfl(g1, r);
        float rx1 = __shfl(g2, r), ry1 = __shfl(g3, r);
        s_gtiou[r * G_ + lane] = iou1(rx0, ry0, rx1, ry1, g0, g1, g2, g3);
    }

    // --- sort keys: descending score, tie -> ascending original index ---
    for (int t = 0; t < SLOTS; ++t) {
        int j = t * 64 + lane;
        int g = pos_gt[b * N_ + j];
        int lab = gt_labels[b * G_ + g];
        int pi = pos_inds[b * N_ + j];
        float s = cls_scores[(size_t)b * (M_ * C_) + (size_t)pi * C_ + lab];
        s_keys[j] = ((ull)(~__float_as_uint(s)) << 32) | (unsigned)j;
    }
    __syncthreads();

    // --- bitonic sort, single wave ---
    for (int k = 2; k <= N_; k <<= 1) {
        for (int jj = k >> 1; jj > 0; jj >>= 1) {
#pragma unroll
            for (int u = 0; u < SLOTS; ++u) {
                int idx = u * 64 + lane;
                if ((idx & jj) == 0) {
                    int partner = idx | jj;
                    ull a = s_keys[idx], c = s_keys[partner];
                    bool up = ((idx & k) == 0);
                    if ((a > c) == up) { s_keys[idx] = c; s_keys[partner] = a; }
                }
            }
            __syncthreads();
        }
    }

    // --- gather, SLOT-MAJOR: lane's slot u = sorted position p = u*64+lane ---
    float bx0[SLOTS], by0[SLOTS], bz1[SLOTS], bw1[SLOTS], a2[SLOTS], sc[SLOTS], I_arr[SLOTS];
    int gti[SLOTS];
#pragma unroll
    for (int u = 0; u < SLOTS; ++u) {
        int p = u * 64 + lane;
        ull key = s_keys[p];
        int j = (int)(unsigned)(key & 0xFFFFFFFFull);
        float s = __uint_as_float(~(unsigned)(key >> 32));
        const float* bp = bbox_preds + (size_t)(b * N_ + j) * 4;
        float x0 = bp[0], y0 = bp[1], x1 = bp[2], y1 = bp[3];
        int g = pos_gt[b * N_ + j];
        float area = (x1 - x0 + 1.0f) * (y1 - y0 + 1.0f);
        bx0[u] = x0; by0[u] = y0; bz1[u] = x1 + 1.0f; bw1[u] = y1 + 1.0f;
        a2[u] = area; sc[u] = s; gti[u] = g; I_arr[u] = 0.f;
        s_elem4[p * 2 + 0] = make_float4(x0, y0, x1, y1);
        s_elem4[p * 2 + 1] = make_float4(__int_as_float(g), s, area, 0.f);
    }
    __syncthreads();

    unsigned mask = 0xFFFFu;   // bit u alive for position u*64+lane
    int seen_flag = 0;
    float sx0 = 0.f, sy0 = 0.f, sx1 = 0.f, sy1 = 0.f;
    float tpull = 0.f, tpush = 0.f;
    int pcnt = 0, qcnt = 0;

    int u0 = 0, l = 0;                 // current pop: slot u0 (frontier), lane l; p = u0*64+l
    float4 cA = s_elem4[0], cB = s_elem4[1];   // position 0 = first pop (mask full)

    while (true) {
        const float ix0 = cA.x, iy0 = cA.y, ix1 = cA.z, iy1 = cA.w;
        const int g = __builtin_amdgcn_readfirstlane(__float_as_int(cB.x));
        const float score_i = cB.y;
        const float a1 = cB.z;

        // seen-state before update; pcnt NOT gated on remaining (matches reference)
        const int hs = __builtin_amdgcn_readlane(seen_flag, g);
        pcnt += hs;
        if (!hs && lane == g) { seen_flag = 1; sx0 = ix0; sy0 = iy0; sx1 = ix1; sy1 = iy1; }

        // remove popped, then 'remaining' (reference order: pre-kill)
        if (lane == l) mask &= ~(1u << u0);
        if (__ballot(mask != 0u) == 0ull) break;   // drop this step's pull/push

        // --- phase 1: branchless kill scan, frontier-skipped (slots < u0 all dead) ---
        const float az1 = ix1 + 1.0f, aw1 = iy1 + 1.0f;
        unsigned kill = 0u;
#define PH1(u) case u: { \
            float lx = fmaxf(ix0, bx0[u]); \
            float ly = fmaxf(iy0, by0[u]); \
            float rx = fminf(az1, bz1[u]); \
            float ry = fminf(aw1, bw1[u]); \
            float w = fmaxf(rx - lx, 0.0f); \
            float h = fmaxf(ry - ly, 0.0f); \
            float I = w * h; \
            I_arr[u] = I; \
            bool c = (3.0f * I > a1 + a2[u]); \
            kill = c ? (kill | (1u << u)) : kill; \
            bx0[u] = c ? 3e37f : bx0[u]; \
        }
        switch (u0) {
            PH1(0)  PH1(1)  PH1(2)  PH1(3)  PH1(4)  PH1(5)  PH1(6)  PH1(7)
            PH1(8)  PH1(9)  PH1(10) PH1(11) PH1(12) PH1(13) PH1(14) PH1(15)
        }
#undef PH1
        mask &= ~kill;

        // --- select next pop + prefetch its element data (latency overlapped below) ---
        const bool have_next = (__ballot(mask != 0u) != 0ull);
        int nu0 = u0, nl = 0;
        float4 nA, nB;
        if (have_next) {
            ull bal;
            while ((bal = __ballot((mask >> nu0) & 1u)) == 0ull) nu0++;
            nl = __ffsll(bal) - 1;
            int p = nu0 * 64 + nl;
            nA = s_elem4[p * 2 + 0];
            nB = s_elem4[p * 2 + 1];
        }

        // --- pull accumulate (remaining true here) ---
        if (hs) {
            float px0 = __int_as_float(__builtin_amdgcn_readlane(__float_as_int(sx0), g));
            float py0 = __int_as_float(__builtin_amdgcn_readlane(__float_as_int(sy0), g));
            float px1 = __int_as_float(__builtin_amdgcn_readlane(__float_as_int(sx1), g));
            float py1 = __int_as_float(__builtin_amdgcn_readlane(__float_as_int(sy1), g));
            float ovpi = iou1(px0, py0, px1, py1, ix0, iy0, ix1, iy1);
            tpull += -__logf(0.5f + fmaxf(ovpi, 1e-6f)) * score_i;
        }

        // --- phase 2: rare push terms (any kill besides the popped element itself) ---
        unsigned self = (lane == l) ? (1u << u0) : 0u;
        unsigned extra = kill & ~self;
        if (__ballot(extra != 0u) != 0ull) {
            int cnt = 0; float ts = 0.f;
#pragma unroll
            for (int u = 0; u < SLOTS; ++u) {
                if ((extra >> u) & 1u) {
                    int gj = gti[u];
                    if (gj != g) {
                        float U = a1 + a2[u] - I_arr[u];
                        float ov = I_arr[u] / U;
                        if (ov > s_gtiou[g * G_ + gj]) { cnt += 1; ts -= __logf(1.0f - ov) * sc[u]; }
                    }
                }
            }
#pragma unroll
            for (int off = 32; off; off >>= 1) {
                cnt += __shfl_xor(cnt, off);
                ts += __shfl_xor(ts, off);
            }
            if (cnt > 0) { tpush += ts / (float)cnt; qcnt += cnt; }
        }

        if (!have_next) break;   // this step accumulated; next step would be a no-op
        u0 = nu0; l = nl; cA = nA; cB = nB;
    }

    if (lane == 0) {
        atomicAdd(&out[0], (tpush / ((float)qcnt + 1e-6f)) * 0.125f);  // mean push, B=8
        atomicAdd(&out[1], (tpull / ((float)pcnt + 1e-6f)) * 0.125f);  // mean pull
    }
}

extern "C" void kernel_launch(void* const* d_in, const int* in_sizes, int n_in,
                              void* d_out, int out_size, void* d_ws, size_t ws_size,
                              hipStream_t stream) {
    const int* pos_inds = (const int*)d_in[0];
    const int* pos_gt = (const int*)d_in[1];
    const float* gt_bboxes = (const float*)d_in[2];
    const float* bbox_preds = (const float*)d_in[3];
    const float* cls_scores = (const float*)d_in[4];
    const int* gt_labels = (const int*)d_in[5];
    float* out = (float*)d_out;

    hipMemsetAsync(out, 0, 2 * sizeof(float), stream);  // d_out re-poisoned 0xAA each call
    nms_loss_kernel<<<dim3(B_), dim3(64), 0, stream>>>(
        pos_inds, pos_gt, gt_bboxes, bbox_preds, cls_scores, gt_labels, out);
}

// Round 4
// 539.752 us; speedup vs baseline: 2.6927x; 2.6927x over previous
//
#include <hip/hip_runtime.h>
#include <math.h>

#define B_ 8
#define N_ 1024
#define M_ 20000
#define C_ 80
#define G_ 64
typedef unsigned long long ull;

// ws layout: gtiou [B][64][64] f32 (128 KB) | elem [B][1024][2] float4 (256 KB)
//            | adj [B][1024][64] u16 (1 MB)  -- total 1.375 MB
#define WS_GTIOU_OFF 0
#define WS_ELEM_OFF  (131072)
#define WS_ADJ_OFF   (131072 + 262144)

__device__ __forceinline__ float iou1(float ax, float ay, float az, float aw,
                                      float bx, float by, float bz, float bw) {
    // legacy +1 convention, exact reference arithmetic order
    float lx = fmaxf(ax, bx), ly = fmaxf(ay, by);
    float rx = fminf(az, bz), ry = fminf(aw, bw);
    float w = fmaxf(rx - lx + 1.0f, 0.0f), h = fmaxf(ry - ly + 1.0f, 0.0f);
    float ov = w * h;
    float a1 = (az - ax + 1.0f) * (aw - ay + 1.0f);
    float a2 = (bz - bx + 1.0f) * (bw - by + 1.0f);
    return ov / (a1 + a2 - ov);
}

// ---- Kernel 1: per-batch scores, bitonic sort, gt-gt IoU, sorted element table ----
__global__ __launch_bounds__(256) void prep_kernel(
    const int* __restrict__ pos_inds, const int* __restrict__ pos_gt,
    const float* __restrict__ gt_bboxes, const float* __restrict__ bbox_preds,
    const float* __restrict__ cls_scores, const int* __restrict__ gt_labels,
    float* __restrict__ gtiouG, float4* __restrict__ elemG) {
    const int b = blockIdx.x, t = threadIdx.x;
    __shared__ ull s_keys[N_];

    for (int j = t; j < N_; j += 256) {
        int g = pos_gt[b * N_ + j];
        int lab = gt_labels[b * G_ + g];
        int pi = pos_inds[b * N_ + j];
        float s = cls_scores[(size_t)b * (M_ * C_) + (size_t)pi * C_ + lab];
        // descending score, tie -> ascending original index (jnp.argmax tie-break)
        s_keys[j] = ((ull)(~__float_as_uint(s)) << 32) | (unsigned)j;
    }
    __syncthreads();

    for (int k = 2; k <= N_; k <<= 1) {
        for (int jj = k >> 1; jj; jj >>= 1) {
            for (int idx = t; idx < N_; idx += 256) {
                if ((idx & jj) == 0) {
                    int pr = idx | jj;
                    ull a = s_keys[idx], c = s_keys[pr];
                    bool up = ((idx & k) == 0);
                    if ((a > c) == up) { s_keys[idx] = c; s_keys[pr] = a; }
                }
            }
            __syncthreads();
        }
    }

    const float* gb = gt_bboxes + (size_t)b * G_ * 4;
    for (int e = t; e < G_ * G_; e += 256) {
        int r = e >> 6, c = e & 63;
        gtiouG[(size_t)b * 4096 + e] =
            iou1(gb[r * 4], gb[r * 4 + 1], gb[r * 4 + 2], gb[r * 4 + 3],
                 gb[c * 4], gb[c * 4 + 1], gb[c * 4 + 2], gb[c * 4 + 3]);
    }

    for (int p = t; p < N_; p += 256) {
        ull key = s_keys[p];
        int j = (int)(unsigned)(key & 0xFFFFFFFFull);
        float s = __uint_as_float(~(unsigned)(key >> 32));   // exact score recovery
        const float* bp = bbox_preds + (size_t)(b * N_ + j) * 4;
        float x0 = bp[0], y0 = bp[1], x1 = bp[2], y1 = bp[3];
        int g = pos_gt[b * N_ + j];
        float area = (x1 - x0 + 1.0f) * (y1 - y0 + 1.0f);
        elemG[(size_t)(b * N_ + p) * 2 + 0] = make_float4(x0, y0, x1, y1);
        elemG[(size_t)(b * N_ + p) * 2 + 1] = make_float4(__int_as_float(g), s, area, 0.f);
    }
}

// ---- Kernel 2: adjacency bits in sorted space: bit = (iou > 0.5), i.e. 3I > a1+a2 ----
__global__ __launch_bounds__(256) void adj_kernel(
    const float4* __restrict__ elemG, unsigned short* __restrict__ adjG) {
    const int b = blockIdx.y;
    const int r = blockIdx.x * 4 + (threadIdx.x >> 6);
    const int lane = threadIdx.x & 63;
    float4 rA = elemG[(size_t)(b * N_ + r) * 2];
    float ax0 = rA.x, ay0 = rA.y;
    float az1 = rA.z + 1.0f, aw1 = rA.w + 1.0f;
    float a1 = (rA.z - rA.x + 1.0f) * (rA.w - rA.y + 1.0f);
    unsigned bits = 0;
#pragma unroll
    for (int u = 0; u < 16; ++u) {
        int cpos = lane * 16 + u;
        float4 cA = elemG[(size_t)(b * N_ + cpos) * 2];
        float lx = fmaxf(ax0, cA.x), ly = fmaxf(ay0, cA.y);
        float rx = fminf(az1, cA.z + 1.0f), ry = fminf(aw1, cA.w + 1.0f);
        float w = fmaxf(rx - lx, 0.0f), h = fmaxf(ry - ly, 0.0f);
        float I = w * h;
        float a2 = (cA.z - cA.x + 1.0f) * (cA.w - cA.y + 1.0f);
        bits |= (3.0f * I > a1 + a2) ? (1u << u) : 0u;
    }
    adjG[(size_t)(b * N_ + r) * 64 + lane] = (unsigned short)bits;
}

// ---- Kernel 3: sequential NMS loop; kill scan replaced by adjacency-row AND ----
__global__ __launch_bounds__(64) void nms_seq_kernel(
    const float4* __restrict__ elemG, const unsigned short* __restrict__ adjG,
    const float* __restrict__ gtiouG, float* __restrict__ out) {
    const int b = blockIdx.x, lane = threadIdx.x;
    __shared__ float4 s_elem4[N_ * 2];          // 32 KB: popped-element broadcast
    __shared__ unsigned short s_adj[128 * 64];  // 16 KB: 128-row rolling window

    // per-lane register copies (rare phase-2 only); also populate s_elem4
    float bx0[16], by0[16], bz1[16], bw1[16], a2[16], sc[16];
    int gti[16];
#pragma unroll
    for (int u = 0; u < 16; ++u) {
        int p = lane * 16 + u;
        float4 eA = elemG[(size_t)(b * N_ + p) * 2];
        float4 eB = elemG[(size_t)(b * N_ + p) * 2 + 1];
        bx0[u] = eA.x; by0[u] = eA.y; bz1[u] = eA.z + 1.0f; bw1[u] = eA.w + 1.0f;
        a2[u] = eB.z; sc[u] = eB.y; gti[u] = __float_as_int(eB.x);
        s_elem4[p * 2] = eA; s_elem4[p * 2 + 1] = eB;
    }
    {   // preload adjacency rows 0..127 (16 KB, lane-linear copy)
        const uint4* asrc = (const uint4*)(adjG + (size_t)b * N_ * 64);
        uint4* adst = (uint4*)s_adj;
        for (int c = 0; c < 16; ++c) adst[c * 64 + lane] = asrc[c * 64 + lane];
    }
    __syncthreads();

    unsigned mask = 0xFFFFu;   // bit u = position lane*16+u alive (lane-major)
    int seen = 0;              // lane g: gt g has a first-seen box
    float sx0 = 0.f, sy0 = 0.f, sx1 = 0.f, sy1 = 0.f;
    float tpull = 0.f, tpush = 0.f;
    int pcnt = 0, qcnt = 0;
    int loaded_hi = 128;
    const float* gt_b = gtiouG + (size_t)b * 4096;

    int p = 0;   // current pop = first alive sorted position; strictly increasing
    while (true) {
        float4 eA = s_elem4[p * 2], eB = s_elem4[p * 2 + 1];
        unsigned row = s_adj[((p & 127) << 6) + lane];
        const int g = __builtin_amdgcn_readfirstlane(__float_as_int(eB.x));
        const float score_i = eB.y, a1 = eB.z;
        const float ix0 = eA.x, iy0 = eA.y, ix1 = eA.z, iy1 = eA.w;

        const int hs = __builtin_amdgcn_readlane(seen, g);
        pcnt += hs;   // NOT gated on remaining (matches reference)
        if (!hs && lane == g) { seen = 1; sx0 = ix0; sy0 = iy0; sx1 = ix1; sy1 = iy1; }

        // remove popped, then 'remaining' (reference order)
        if (lane == (p >> 4)) mask &= ~(1u << (p & 15));
        if (__ballot(mask != 0u) == 0ull) break;   // drop this step's pull/push

        unsigned kill = row & mask;   // state-independent bits & alive
        mask &= ~kill;

        if (hs) {   // pull vs first-seen box of gt g
            float px0 = __int_as_float(__builtin_amdgcn_readlane(__float_as_int(sx0), g));
            float py0 = __int_as_float(__builtin_amdgcn_readlane(__float_as_int(sy0), g));
            float px1 = __int_as_float(__builtin_amdgcn_readlane(__float_as_int(sx1), g));
            float py1 = __int_as_float(__builtin_amdgcn_readlane(__float_as_int(sy1), g));
            float ovpi = iou1(px0, py0, px1, py1, ix0, iy0, ix1, iy1);
            tpull += -__logf(0.5f + fmaxf(ovpi, 1e-6f)) * score_i;
        }

        if (__ballot(kill != 0u) != 0ull) {   // rare push terms
            int cnt = 0; float ts = 0.f;
            float az1 = ix1 + 1.0f, aw1 = iy1 + 1.0f;
#pragma unroll
            for (int u = 0; u < 16; ++u) {
                if ((kill >> u) & 1u) {
                    int gj = gti[u];
                    if (gj != g) {
                        float lx = fmaxf(ix0, bx0[u]), ly = fmaxf(iy0, by0[u]);
                        float rx = fminf(az1, bz1[u]), ry = fminf(aw1, bw1[u]);
                        float w = fmaxf(rx - lx, 0.0f), h = fmaxf(ry - ly, 0.0f);
                        float I = w * h;
                        float ov = I / (a1 + a2[u] - I);
                        if (ov > gt_b[g * 64 + gj]) { cnt += 1; ts -= __logf(1.0f - ov) * sc[u]; }
                    }
                }
            }
#pragma unroll
            for (int off = 32; off; off >>= 1) {
                cnt += __shfl_xor(cnt, off);
                ts += __shfl_xor(ts, off);
            }
            if (cnt > 0) { tpush += ts / (float)cnt; qcnt += cnt; }
        }

        ull bal = __ballot(mask != 0u);
        if (bal == 0ull) break;   // kills emptied the set; this step already accumulated
        int l = __ffsll(bal) - 1;
        unsigned ml = (unsigned)__builtin_amdgcn_readlane((int)mask, l);
        p = l * 16 + (__ffs((int)ml) - 1);

        // window refill: keep rows [.., loaded_hi) resident, 64 rows ahead of frontier.
        // Overwritten rows are < p (monotone pops) => dead. Copy is synchronous.
        while (loaded_hi < N_ && p + 64 > loaded_hi) {
            const uint4* rs = (const uint4*)(adjG + (size_t)b * N_ * 64 + (size_t)loaded_hi * 64);
            uint4* rd = (uint4*)(s_adj + ((loaded_hi & 127) << 6));
            for (int c = 0; c < 8; ++c) rd[c * 64 + lane] = rs[c * 64 + lane];
            loaded_hi += 64;
        }
    }

    if (lane == 0) {
        atomicAdd(&out[0], (tpush / ((float)qcnt + 1e-6f)) * 0.125f);  // mean push, B=8
        atomicAdd(&out[1], (tpull / ((float)pcnt + 1e-6f)) * 0.125f);  // mean pull
    }
}

extern "C" void kernel_launch(void* const* d_in, const int* in_sizes, int n_in,
                              void* d_out, int out_size, void* d_ws, size_t ws_size,
                              hipStream_t stream) {
    const int* pos_inds = (const int*)d_in[0];
    const int* pos_gt = (const int*)d_in[1];
    const float* gt_bboxes = (const float*)d_in[2];
    const float* bbox_preds = (const float*)d_in[3];
    const float* cls_scores = (const float*)d_in[4];
    const int* gt_labels = (const int*)d_in[5];
    float* out = (float*)d_out;

    float* gtiouG = (float*)((char*)d_ws + WS_GTIOU_OFF);
    float4* elemG = (float4*)((char*)d_ws + WS_ELEM_OFF);
    unsigned short* adjG = (unsigned short*)((char*)d_ws + WS_ADJ_OFF);

    hipMemsetAsync(out, 0, 2 * sizeof(float), stream);  // d_out re-poisoned 0xAA each call
    prep_kernel<<<dim3(B_), dim3(256), 0, stream>>>(
        pos_inds, pos_gt, gt_bboxes, bbox_preds, cls_scores, gt_labels, gtiouG, elemG);
    adj_kernel<<<dim3(256, B_), dim3(256), 0, stream>>>(elemG, adjG);
    nms_seq_kernel<<<dim3(B_), dim3(64), 0, stream>>>(elemG, adjG, gtiouG, out);
}